// Round 4
// baseline (202.626 us; speedup 1.0000x reference)
//
#include <hip/hip_runtime.h>

#define B_ 16
#define N_ 2048
#define M_ 2048
#define D_ 64
#define SCALE 0.125f
#define MSLICE 512   // M_/4: per-wave m-slice

typedef short sv8 __attribute__((ext_vector_type(8)));
typedef short sv4 __attribute__((ext_vector_type(4)));
typedef float fv4 __attribute__((ext_vector_type(4)));

__device__ __forceinline__ short f2bf(float x) {
    union { float f; unsigned u; } a; a.f = x;
    unsigned r = a.u + 0x7FFFu + ((a.u >> 16) & 1u);
    return (short)(r >> 16);
}
__device__ __forceinline__ unsigned cvtpk(float lo, float hi) {
    unsigned r;
    asm("v_cvt_pk_bf16_f32 %0, %1, %2" : "=v"(r) : "v"(lo), "v"(hi));
    return r;
}
__device__ __forceinline__ float bflo(unsigned u) { return __uint_as_float(u << 16); }
__device__ __forceinline__ float bfhi(unsigned u) { return __uint_as_float(u & 0xffff0000u); }

// fp32 -> bf16 (RNE), 4 elems/thread
__global__ void conv_bf16(const float* __restrict__ in, short* __restrict__ outb) {
    int i = (blockIdx.x * 256 + threadIdx.x) * 4;
    float4 f = *(const float4*)(in + i);
    uint2 o; o.x = cvtpk(f.x, f.y); o.y = cvtpk(f.z, f.w);
    *(uint2*)(outb + i) = o;
}

// v[b][m][d] fp32 -> vt[b][d][m] bf16, 64x64 tiles through LDS
__global__ void conv_vt(const float* __restrict__ v, short* __restrict__ vt) {
    __shared__ short tile[64][65];
    int t = threadIdx.x;
    int b = blockIdx.x >> 5;
    int mt = (blockIdx.x & 31) << 6;
    for (int i = 0; i < 4; ++i) {
        int idx = i * 256 + t;
        int m = idx >> 4;
        int dq = (idx & 15) << 2;
        float4 f = *(const float4*)(v + ((size_t)(b * M_ + mt + m) * D_ + dq));
        tile[m][dq + 0] = f2bf(f.x); tile[m][dq + 1] = f2bf(f.y);
        tile[m][dq + 2] = f2bf(f.z); tile[m][dq + 3] = f2bf(f.w);
    }
    __syncthreads();
    for (int j = 0; j < 2; ++j) {
        int idx = j * 256 + t;
        int d = idx >> 3;
        int mq = (idx & 7) << 3;
        sv4 o0, o1;
        #pragma unroll
        for (int c = 0; c < 4; ++c) o0[c] = tile[mq + c][d];
        #pragma unroll
        for (int c = 0; c < 4; ++c) o1[c] = tile[mq + 4 + c][d];
        short* dst = vt + ((size_t)(b * D_ + d) * M_ + mt + mq);
        *(sv4*)(dst) = o0;
        *(sv4*)(dst + 4) = o1;
    }
}

// Pass 1: softmax denominators. Block = 16 rows; 4 waves each take an m-slice
// of 512; cross-wave reduce through tiny LDS. Grid = B * N/16 = 2048 blocks.
__global__ __launch_bounds__(256, 6) void attn_sums(
    const short* __restrict__ Qb, const short* __restrict__ Kb,
    float* __restrict__ rinv_g)
{
    __shared__ float l_sh[4][16];
    const int tid = threadIdx.x;
    const int w = tid >> 6, lane = tid & 63;
    const int r = lane & 15, g = lane >> 4;
    const int b = blockIdx.x >> 7;
    const int n0 = (blockIdx.x & 127) << 4;

    const short* qbase = Qb + ((b * N_ + n0 + r) * D_ + g * 8);
    sv8 q0 = *(const sv8*)(qbase);
    sv8 q1 = *(const sv8*)(qbase + 32);
    const short* kbb = Kb + (size_t)b * M_ * D_;

    float lsum = 0.f;
    for (int m0 = w * MSLICE; m0 < (w + 1) * MSLICE; m0 += 64) {
        #pragma unroll
        for (int s = 0; s < 4; ++s) {
            const short* ka = kbb + (m0 + s * 16 + r) * D_ + g * 8;
            sv8 k0 = *(const sv8*)ka;
            sv8 k1 = *(const sv8*)(ka + 32);
            fv4 acc = {0.f, 0.f, 0.f, 0.f};
            acc = __builtin_amdgcn_mfma_f32_16x16x32_bf16(k0, q0, acc, 0, 0, 0);
            acc = __builtin_amdgcn_mfma_f32_16x16x32_bf16(k1, q1, acc, 0, 0, 0);
            lsum += __expf(acc[0] * SCALE) + __expf(acc[1] * SCALE)
                  + __expf(acc[2] * SCALE) + __expf(acc[3] * SCALE);
        }
    }
    lsum += __shfl_xor(lsum, 16, 64);
    lsum += __shfl_xor(lsum, 32, 64);
    if (g == 0) l_sh[w][r] = lsum;
    __syncthreads();
    if (tid < 16) {
        float s = (l_sh[0][tid] + l_sh[1][tid]) + (l_sh[2][tid] + l_sh[3][tid]);
        rinv_g[b * N_ + n0 + tid] = 1.f / s;
    }
}

// Pass 2: block = 16 rows, wave w handles m-slice [w*512,(w+1)*512):
//   S^T MFMA -> exp -> cvt_pk -> wave-private swizzled LDS tile
//   -> transposed nontemporal attn stores + PV MFMA partials.
// After the loop: PV partials reduced across the 4 waves via the same LDS.
__global__ __launch_bounds__(256, 4) void attn_bulk(
    const short* __restrict__ Qb, const short* __restrict__ Kb,
    const short* __restrict__ Vt, const float* __restrict__ rinv_g,
    float* __restrict__ outp, float* __restrict__ attnp)
{
    __shared__ char smem[16384];   // wave w: [w*4KB, w*4KB+4KB) = P dbuf, then out-reduce

    const int tid = threadIdx.x;
    const int w = tid >> 6, lane = tid & 63;
    const int r = lane & 15, g = lane >> 4;
    const int b = blockIdx.x >> 7;
    const int n0 = (blockIdx.x & 127) << 4;

    const short* qbase = Qb + ((b * N_ + n0 + r) * D_ + g * 8);
    sv8 q0 = *(const sv8*)(qbase);
    sv8 q1 = *(const sv8*)(qbase + 32);

    float rinv = rinv_g[b * N_ + n0 + r];
    const int n_st = lane >> 2, mq = lane & 3;
    float rinv_st = __shfl(rinv, n_st, 64);

    char* lds = smem + (w << 12);

    // byte = n*128 + ((m>>3 ^ (n&7))<<4) + (m&7)*2   (within 2KB buffer)
    int wb[4], ra[2], ab[4];
    #pragma unroll
    for (int s = 0; s < 4; ++s)
        wb[s] = r * 128 + (((s * 2 + (g >> 1)) ^ (r & 7)) << 4) + ((g & 1) * 8);
    #pragma unroll
    for (int c = 0; c < 2; ++c)
        ra[c] = r * 128 + (((c * 4 + g) ^ (r & 7)) << 4);
    #pragma unroll
    for (int c2 = 0; c2 < 4; ++c2)
        ab[c2] = n_st * 128 + (((c2 * 2 + (mq >> 1)) ^ (n_st & 7)) << 4) + ((mq & 1) * 8);

    fv4 ac0 = {0.f,0.f,0.f,0.f}, ac1 = {0.f,0.f,0.f,0.f};
    fv4 ac2 = {0.f,0.f,0.f,0.f}, ac3 = {0.f,0.f,0.f,0.f};

    const short* kbb = Kb + (size_t)b * M_ * D_;
    const short* vbb = Vt + (size_t)b * D_ * M_;
    float* arow = attnp + (size_t)(b * N_ + n0 + n_st) * M_ + mq * 4;

    int buf = 0;
    for (int m0 = w * MSLICE; m0 < (w + 1) * MSLICE; m0 += 64, buf ^= 1) {
        char* ldsb = lds + (buf << 11);

        #pragma unroll
        for (int s = 0; s < 4; ++s) {
            const short* ka = kbb + (m0 + s * 16 + r) * D_ + g * 8;
            sv8 k0 = *(const sv8*)ka;
            sv8 k1 = *(const sv8*)(ka + 32);
            fv4 acc = {0.f, 0.f, 0.f, 0.f};
            acc = __builtin_amdgcn_mfma_f32_16x16x32_bf16(k0, q0, acc, 0, 0, 0);
            acc = __builtin_amdgcn_mfma_f32_16x16x32_bf16(k1, q1, acc, 0, 0, 0);
            float p0 = __expf(acc[0] * SCALE), p1 = __expf(acc[1] * SCALE);
            float p2 = __expf(acc[2] * SCALE), p3 = __expf(acc[3] * SCALE);
            uint2 pk; pk.x = cvtpk(p0, p1); pk.y = cvtpk(p2, p3);
            *(uint2*)(ldsb + wb[s]) = pk;
        }

        // transposed, normalized attn stores
        #pragma unroll
        for (int c2 = 0; c2 < 4; ++c2) {
            uint2 pv = *(const uint2*)(ldsb + ab[c2]);
            fv4 o;
            o[0] = bflo(pv.x) * rinv_st; o[1] = bfhi(pv.x) * rinv_st;
            o[2] = bflo(pv.y) * rinv_st; o[3] = bfhi(pv.y) * rinv_st;
            __builtin_nontemporal_store(o, (fv4*)(arow + m0 + c2 * 16));
        }

        // PV partial accumulate over this wave's m-slice
        #pragma unroll
        for (int c = 0; c < 2; ++c) {
            sv8 pa = *(const sv8*)(ldsb + ra[c]);
            const short* vb0 = vbb + r * M_ + m0 + c * 32 + g * 8;
            ac0 = __builtin_amdgcn_mfma_f32_16x16x32_bf16(pa, *(const sv8*)(vb0),            ac0, 0, 0, 0);
            ac1 = __builtin_amdgcn_mfma_f32_16x16x32_bf16(pa, *(const sv8*)(vb0 + 16 * M_), ac1, 0, 0, 0);
            ac2 = __builtin_amdgcn_mfma_f32_16x16x32_bf16(pa, *(const sv8*)(vb0 + 32 * M_), ac2, 0, 0, 0);
            ac3 = __builtin_amdgcn_mfma_f32_16x16x32_bf16(pa, *(const sv8*)(vb0 + 48 * M_), ac3, 0, 0, 0);
        }
    }

    // cross-wave PV reduction through LDS (reuse P region; wave-private until barrier)
    float* red = (float*)(smem) + (w << 10);   // 1024 floats per wave: [row][d]
    #pragma unroll
    for (int reg = 0; reg < 4; ++reg) {
        int row = g * 4 + reg;
        red[row * 64 +  0 + r] = ac0[reg];
        red[row * 64 + 16 + r] = ac1[reg];
        red[row * 64 + 32 + r] = ac2[reg];
        red[row * 64 + 48 + r] = ac3[reg];
    }
    __syncthreads();
    {
        int row = tid >> 4, dq = (tid & 15) << 2;
        const float* f0 = (const float*)smem;
        fv4 s0 = *(const fv4*)(f0 +        row * 64 + dq);
        fv4 s1 = *(const fv4*)(f0 + 1024 + row * 64 + dq);
        fv4 s2 = *(const fv4*)(f0 + 2048 + row * 64 + dq);
        fv4 s3 = *(const fv4*)(f0 + 3072 + row * 64 + dq);
        float ri = rinv_g[b * N_ + n0 + row];
        fv4 o;
        o[0] = ((s0[0] + s1[0]) + (s2[0] + s3[0])) * ri;
        o[1] = ((s0[1] + s1[1]) + (s2[1] + s3[1])) * ri;
        o[2] = ((s0[2] + s1[2]) + (s2[2] + s3[2])) * ri;
        o[3] = ((s0[3] + s1[3]) + (s2[3] + s3[3])) * ri;
        __builtin_nontemporal_store(o, (fv4*)(outp + (size_t)(b * N_ + n0 + row) * D_ + dq));
    }
}

extern "C" void kernel_launch(void* const* d_in, const int* in_sizes, int n_in,
                              void* d_out, int out_size, void* d_ws, size_t ws_size,
                              hipStream_t stream) {
    const float* q = (const float*)d_in[0];
    const float* k = (const float*)d_in[1];
    const float* v = (const float*)d_in[2];
    float* outp = (float*)d_out;
    float* attnp = outp + (size_t)B_ * N_ * D_;

    short* Qb = (short*)d_ws;                       // 4 MiB
    short* Kb = Qb + (size_t)B_ * N_ * D_;          // 4 MiB
    short* Vt = Kb + (size_t)B_ * M_ * D_;          // 4 MiB (transposed [b][d][m])
    float* rinv_g = (float*)(Vt + (size_t)B_ * M_ * D_);  // 128 KiB

    conv_bf16<<<2048, 256, 0, stream>>>(q, Qb);
    conv_bf16<<<2048, 256, 0, stream>>>(k, Kb);
    conv_vt<<<512, 256, 0, stream>>>(v, Vt);
    attn_sums<<<B_ * (N_ / 16), 256, 0, stream>>>(Qb, Kb, rinv_g);
    attn_bulk<<<B_ * (N_ / 16), 256, 0, stream>>>(Qb, Kb, Vt, rinv_g, outp, attnp);
}

// Round 8
// 197.628 us; speedup vs baseline: 1.0253x; 1.0253x over previous
//
#include <hip/hip_runtime.h>

#define B_ 16
#define N_ 2048
#define M_ 2048
#define D_ 64
#define SCALE 0.125f

typedef short sv8 __attribute__((ext_vector_type(8)));
typedef short sv4 __attribute__((ext_vector_type(4)));
typedef float fv4 __attribute__((ext_vector_type(4)));

__device__ __forceinline__ short f2bf(float x) {
    union { float f; unsigned u; } a; a.f = x;
    unsigned r = a.u + 0x7FFFu + ((a.u >> 16) & 1u);
    return (short)(r >> 16);
}
__device__ __forceinline__ unsigned cvtpk(float lo, float hi) {
    unsigned r;
    asm("v_cvt_pk_bf16_f32 %0, %1, %2" : "=v"(r) : "v"(lo), "v"(hi));
    return r;
}
__device__ __forceinline__ float bflo(unsigned u) { return __uint_as_float(u << 16); }
__device__ __forceinline__ float bfhi(unsigned u) { return __uint_as_float(u & 0xffff0000u); }

// fp32 -> bf16 (RNE), 4 elems/thread
__global__ void conv_bf16(const float* __restrict__ in, short* __restrict__ outb) {
    int i = (blockIdx.x * 256 + threadIdx.x) * 4;
    float4 f = *(const float4*)(in + i);
    uint2 o; o.x = cvtpk(f.x, f.y); o.y = cvtpk(f.z, f.w);
    *(uint2*)(outb + i) = o;
}

// v[b][m][d] fp32 -> vt[b][d][m] bf16, 64x64 tiles through LDS
__global__ void conv_vt(const float* __restrict__ v, short* __restrict__ vt) {
    __shared__ short tile[64][65];
    int t = threadIdx.x;
    int b = blockIdx.x >> 5;
    int mt = (blockIdx.x & 31) << 6;
    for (int i = 0; i < 4; ++i) {
        int idx = i * 256 + t;
        int m = idx >> 4;
        int dq = (idx & 15) << 2;
        float4 f = *(const float4*)(v + ((size_t)(b * M_ + mt + m) * D_ + dq));
        tile[m][dq + 0] = f2bf(f.x); tile[m][dq + 1] = f2bf(f.y);
        tile[m][dq + 2] = f2bf(f.z); tile[m][dq + 3] = f2bf(f.w);
    }
    __syncthreads();
    for (int j = 0; j < 2; ++j) {
        int idx = j * 256 + t;
        int d = idx >> 3;
        int mq = (idx & 7) << 3;
        sv4 o0, o1;
        #pragma unroll
        for (int c = 0; c < 4; ++c) o0[c] = tile[mq + c][d];
        #pragma unroll
        for (int c = 0; c < 4; ++c) o1[c] = tile[mq + 4 + c][d];
        short* dst = vt + ((size_t)(b * D_ + d) * M_ + mt + mq);
        *(sv4*)(dst) = o0;
        *(sv4*)(dst + 4) = o1;
    }
}

// Fused attention, DIRECT global K/V reads (R3-validated paths), no LDS staging.
// Block = 64 rows (4 waves x 16 rows), each wave sweeps full M. No barriers.
// Pass A: row sums -> rinv_sh (per-wave).  Pass B: attn (256B-run stores) + PV.
__global__ __launch_bounds__(256) void attn_fused(
    const short* __restrict__ Qb, const short* __restrict__ Kb,
    const short* __restrict__ Vt,
    float* __restrict__ outp, float* __restrict__ attnp)
{
    __shared__ short Pb[4][2][16][64];   // [wave][dbuf][n][m], XOR-chunk swizzled
    __shared__ float rinv_sh[4][16];

    const int tid = threadIdx.x;
    const int w = tid >> 6, lane = tid & 63;
    const int r = lane & 15, g = lane >> 4;

    const int b = blockIdx.x >> 5;
    const int n0 = (blockIdx.x & 31) << 6;
    const int nw = n0 + w * 16;

    const short* qbase = Qb + ((b * N_ + nw + r) * D_ + g * 8);
    sv8 q0 = *(const sv8*)(qbase);
    sv8 q1 = *(const sv8*)(qbase + 32);

    const short* kbb = Kb + (size_t)b * M_ * D_;
    const short* vbb = Vt + (size_t)b * D_ * M_;

    // ================= Pass A: denominators =================
    float lsum = 0.f;
    for (int m0 = 0; m0 < M_; m0 += 64) {
        #pragma unroll
        for (int s = 0; s < 4; ++s) {
            const short* ka = kbb + (m0 + s * 16 + r) * D_ + g * 8;
            sv8 k0 = *(const sv8*)ka;
            sv8 k1 = *(const sv8*)(ka + 32);
            fv4 acc = {0.f, 0.f, 0.f, 0.f};
            acc = __builtin_amdgcn_mfma_f32_16x16x32_bf16(k0, q0, acc, 0, 0, 0);
            acc = __builtin_amdgcn_mfma_f32_16x16x32_bf16(k1, q1, acc, 0, 0, 0);
            lsum += __expf(acc[0] * SCALE) + __expf(acc[1] * SCALE)
                  + __expf(acc[2] * SCALE) + __expf(acc[3] * SCALE);
        }
    }
    lsum += __shfl_xor(lsum, 16, 64);
    lsum += __shfl_xor(lsum, 32, 64);
    if (g == 0) rinv_sh[w][r] = 1.f / lsum;

    // ================= Pass B: attn + PV =================
    fv4 ac0 = {0.f,0.f,0.f,0.f}, ac1 = {0.f,0.f,0.f,0.f};
    fv4 ac2 = {0.f,0.f,0.f,0.f}, ac3 = {0.f,0.f,0.f,0.f};

    char* pbase = (char*)&Pb[w][0][0][0];

    // P-tile swizzle: byte = n*128 + ((chunk ^ (n&7))<<4) + sub8  (chunk = m/8 in 16B units)
    int wb[4], ra[2];
    #pragma unroll
    for (int s = 0; s < 4; ++s)
        wb[s] = r * 128 + (((s * 2 + (g >> 1)) ^ (r & 7)) << 4) + ((g & 1) * 8);
    #pragma unroll
    for (int c = 0; c < 2; ++c)
        ra[c] = r * 128 + (((c * 4 + g) ^ (r & 7)) << 4);

    int buf = 0;
    for (int m0 = 0; m0 < M_; m0 += 64, buf ^= 1) {
        char* pb = pbase + (buf << 11);

        // QK^T -> exp -> Pb (wave-private, swizzled); K frags direct from global
        #pragma unroll
        for (int s = 0; s < 4; ++s) {
            const short* ka = kbb + (m0 + s * 16 + r) * D_ + g * 8;
            sv8 k0 = *(const sv8*)ka;
            sv8 k1 = *(const sv8*)(ka + 32);
            fv4 acc = {0.f, 0.f, 0.f, 0.f};
            acc = __builtin_amdgcn_mfma_f32_16x16x32_bf16(k0, q0, acc, 0, 0, 0);
            acc = __builtin_amdgcn_mfma_f32_16x16x32_bf16(k1, q1, acc, 0, 0, 0);
            float p0 = __expf(acc[0] * SCALE), p1 = __expf(acc[1] * SCALE);
            float p2 = __expf(acc[2] * SCALE), p3 = __expf(acc[3] * SCALE);
            uint2 pk; pk.x = cvtpk(p0, p1); pk.y = cvtpk(p2, p3);
            *(uint2*)(pb + wb[s]) = pk;
        }

        // attn stores: 4 instrs; each = 4 rows (g) x 16 lanes (r) x 16B = 256B runs
        #pragma unroll
        for (int t = 0; t < 4; ++t) {
            const int nr = t * 4 + g;
            uint2 pv = *(const uint2*)(pb + nr * 128 + (((r >> 1) ^ (nr & 7)) << 4) + ((r & 1) * 8));
            float ri = rinv_sh[w][nr];
            fv4 o;
            o[0] = bflo(pv.x) * ri; o[1] = bfhi(pv.x) * ri;
            o[2] = bflo(pv.y) * ri; o[3] = bfhi(pv.y) * ri;
            __builtin_nontemporal_store(o,
                (fv4*)(attnp + (size_t)(b * N_ + nw + nr) * M_ + m0 + r * 4));
        }

        // PV accumulate: P frags from Pb, V frags direct from global (R3 path)
        #pragma unroll
        for (int c = 0; c < 2; ++c) {
            sv8 pa = *(const sv8*)(pb + ra[c]);
            const short* vb0 = vbb + r * M_ + m0 + c * 32 + g * 8;
            ac0 = __builtin_amdgcn_mfma_f32_16x16x32_bf16(pa, *(const sv8*)(vb0),           ac0, 0, 0, 0);
            ac1 = __builtin_amdgcn_mfma_f32_16x16x32_bf16(pa, *(const sv8*)(vb0 + 16 * M_), ac1, 0, 0, 0);
            ac2 = __builtin_amdgcn_mfma_f32_16x16x32_bf16(pa, *(const sv8*)(vb0 + 32 * M_), ac2, 0, 0, 0);
            ac3 = __builtin_amdgcn_mfma_f32_16x16x32_bf16(pa, *(const sv8*)(vb0 + 48 * M_), ac3, 0, 0, 0);
        }
    }

    // epilogue: out[n][d] = acc * rinv[n];  n = g*4+reg, d = {0,16,32,48} + r
    float* obase = outp + (size_t)(b * N_ + nw + g * 4) * D_ + r;
    #pragma unroll
    for (int reg = 0; reg < 4; ++reg) {
        float ri = rinv_sh[w][g * 4 + reg];
        __builtin_nontemporal_store(ac0[reg] * ri, obase + reg * D_);
        __builtin_nontemporal_store(ac1[reg] * ri, obase + reg * D_ + 16);
        __builtin_nontemporal_store(ac2[reg] * ri, obase + reg * D_ + 32);
        __builtin_nontemporal_store(ac3[reg] * ri, obase + reg * D_ + 48);
    }
}

extern "C" void kernel_launch(void* const* d_in, const int* in_sizes, int n_in,
                              void* d_out, int out_size, void* d_ws, size_t ws_size,
                              hipStream_t stream) {
    const float* q = (const float*)d_in[0];
    const float* k = (const float*)d_in[1];
    const float* v = (const float*)d_in[2];
    float* outp = (float*)d_out;
    float* attnp = outp + (size_t)B_ * N_ * D_;

    short* Qb = (short*)d_ws;                       // 4 MiB
    short* Kb = Qb + (size_t)B_ * N_ * D_;          // 4 MiB
    short* Vt = Kb + (size_t)B_ * M_ * D_;          // 4 MiB (transposed [b][d][m])

    conv_bf16<<<2048, 256, 0, stream>>>(q, Qb);
    conv_bf16<<<2048, 256, 0, stream>>>(k, Kb);
    conv_vt<<<512, 256, 0, stream>>>(v, Vt);
    attn_fused<<<B_ * (N_ / 64), 256, 0, stream>>>(Qb, Kb, Vt, outp, attnp);
}